// Round 14
// baseline (740.775 us; speedup 1.0000x reference)
//
#include <hip/hip_runtime.h>
#include <math.h>

#define N_NODES 100000
#define N_EDGES 1600000
#define IN_DIM 500
#define HID 64
#define NCLS 16
#define KP 512     // padded K for layer-1 GEMM
#define NSTEPS 16  // KP/32
#define NBUK 391     // buckets of 256 dsts: bucket = dst >> 8
#define NPAD (NBUK * 256)
#define EPB 8192     // edges per bucket-phase block (512 threads)
#define NT 391       // k1 row tiles of 256 rows
#define BROW 520     // padded Bs row (ushorts): 512 + 8 -> 2-way banks only

typedef __attribute__((ext_vector_type(8))) short short8;
typedef __attribute__((ext_vector_type(4))) float f32x4;

__device__ __forceinline__ unsigned short f2bf(float f) {
    unsigned u = __builtin_bit_cast(unsigned, f);
    return (unsigned short)((u + 0x7FFFu + ((u >> 16) & 1u)) >> 16);
}
__device__ __forceinline__ float bf2f(unsigned short s) {
    unsigned u = ((unsigned)s) << 16;
    return __builtin_bit_cast(float, u);
}
__device__ __forceinline__ unsigned pack2(unsigned short a, unsigned short b) {
    return (unsigned)a | ((unsigned)b << 16);
}

// ---------------------------------------------------------------------------
// K0: build Bt[192][512] bf16, PANEL ORDER: row p*96+q, q<32 -> w1[0] col
// p*32+q; q<64 -> w1[1] col p*32+q-32; q<96 -> root col p*32+q-64. Zero-pad K.
// Panel p thus holds xw0/xw1 cols [p*32,p*32+32) (pack-pair in same panel,
// same lane) and root cols [p*32,p*32+32).
// ---------------------------------------------------------------------------
__global__ __launch_bounds__(256) void k0_bt(
    const float* __restrict__ w1, const float* __restrict__ root1,
    unsigned short* __restrict__ Bt)
{
    const int b = blockIdx.x;  // 0..191
    const int p = b / 96, q = b % 96;
    const float* src;
    int c;
    if (q < 32)       { src = w1;                c = p * 32 + q; }
    else if (q < 64)  { src = w1 + IN_DIM * HID; c = p * 32 + q - 32; }
    else              { src = root1;             c = p * 32 + q - 64; }
    for (int k = threadIdx.x; k < KP; k += 256) {
        float v = (k < IN_DIM) ? src[k * HID + c] : 0.f;
        Bt[b * KP + k] = f2bf(v);
    }
}

// ---------------------------------------------------------------------------
// CSR build, bucket-level (unchanged from R11 baseline).
// ---------------------------------------------------------------------------
__global__ __launch_bounds__(512) void csr_bzero(int* __restrict__ bkcnt)
{
    if (threadIdx.x < NBUK) bkcnt[threadIdx.x] = 0;
}

__global__ __launch_bounds__(512) void csr_bhist(
    const int* __restrict__ ei, int* __restrict__ bkcnt)
{
    __shared__ int h[NBUK];
    const int tid = threadIdx.x;
    for (int i = tid; i < NBUK; i += 512) h[i] = 0;
    __syncthreads();
    const int start = blockIdx.x * EPB;
    const int eend = min(start + EPB, N_EDGES);
#pragma unroll
    for (int j = 0; j < EPB / 512; ++j) {
        const int e = start + j * 512 + tid;
        if (e < eend) atomicAdd(&h[ei[N_EDGES + e] >> 8], 1);
    }
    __syncthreads();
    for (int i = tid; i < NBUK; i += 512)
        if (h[i]) atomicAdd(&bkcnt[i], h[i]);
}

__global__ __launch_bounds__(512) void csr_bscan(
    const int* __restrict__ bkcnt, int* __restrict__ bkoff, int* __restrict__ bkcur)
{
    __shared__ int s[512];
    const int t = threadIdx.x;
    const int val = (t < NBUK) ? bkcnt[t] : 0;
    s[t] = val;
    for (int d = 1; d < 512; d <<= 1) {
        __syncthreads();
        int add = (t >= d) ? s[t - d] : 0;
        __syncthreads();
        s[t] += add;
    }
    __syncthreads();
    if (t < NBUK) {
        const int o = s[t] - val;
        bkoff[t] = o;
        bkcur[t] = o;
    }
    if (t == NBUK - 1) bkoff[NBUK] = s[t];  // == N_EDGES
}

__global__ __launch_bounds__(512) void csr_bucket(
    const int* __restrict__ ei, const float* __restrict__ ea,
    int* __restrict__ bkcur, uint2* __restrict__ epk)
{
    __shared__ int hcnt[NBUK];
    __shared__ int hbase[NBUK];

    const int tid = threadIdx.x;
    const int start = blockIdx.x * EPB;
    const int eend = min(start + EPB, N_EDGES);

    for (int i = tid; i < NBUK; i += 512) hcnt[i] = 0;
    __syncthreads();

#pragma unroll
    for (int j = 0; j < EPB / 512; ++j) {
        const int e = start + j * 512 + tid;
        if (e < eend) atomicAdd(&hcnt[ei[N_EDGES + e] >> 8], 1);
    }
    __syncthreads();

    for (int b = tid; b < NBUK; b += 512) {
        const int c = hcnt[b];
        hbase[b] = c ? atomicAdd(&bkcur[b], c) : 0;
    }
    __syncthreads();
    for (int i = tid; i < NBUK; i += 512) hcnt[i] = 0;
    __syncthreads();

#pragma unroll
    for (int j = 0; j < EPB / 512; ++j) {
        const int e = start + j * 512 + tid;
        if (e < eend) {
            const int src = ei[e];
            const int dst = ei[N_EDGES + e];
            const float v = fminf(fmaxf(ea[e], 0.f), 1.f - 1e-6f);
            const unsigned vq = (unsigned)(v * 16777216.0f);  // 24-bit fixed
            const int bk = dst >> 8;
            const int r = atomicAdd(&hcnt[bk], 1);
            epk[hbase[bk] + r] =
                make_uint2((unsigned)src, ((unsigned)(dst & 255) << 24) | vq);
        }
    }
}

__global__ __launch_bounds__(256) void csr_place(
    const int* __restrict__ bkoff, const uint2* __restrict__ epk,
    uint2* __restrict__ epkS, int* __restrict__ off)
{
    __shared__ int hist[256];
    __shared__ int sc[256];
    __shared__ int cur[256];

    const int b = blockIdx.x;
    const int tid = threadIdx.x;
    const int start = bkoff[b];
    const int end = bkoff[b + 1];
    const int cnt = end - start;

    hist[tid] = 0;
    __syncthreads();
    for (int i = tid; i < cnt; i += 256)
        atomicAdd(&hist[epk[start + i].y >> 24], 1);
    __syncthreads();

    const int val = hist[tid];
    sc[tid] = val;
    for (int d = 1; d < 256; d <<= 1) {
        __syncthreads();
        int add = (tid >= d) ? sc[tid - d] : 0;
        __syncthreads();
        sc[tid] += add;
    }
    __syncthreads();
    const int mystart = start + sc[tid] - val;  // exclusive
    off[(b << 8) + tid] = mystart;
    cur[tid] = mystart;
    __syncthreads();

    for (int i = tid; i < cnt; i += 256) {
        const uint2 u = epk[start + i];
        const int dl = u.y >> 24;
        const float v = (float)(u.y & 0xFFFFFFu) * 5.9604644775390625e-8f;
        const int pos = atomicAdd(&cur[dl], 1);
        epkS[pos] = make_uint2(u.x, __builtin_bit_cast(unsigned, v));
    }
}

// ---------------------------------------------------------------------------
// K1: bf16 MFMA GEMM — B-PANEL RESIDENT IN LDS, BARRIER-FREE K-LOOP.
// Block = 1024 threads (16 waves, 4/SIMD), panel p = blockIdx&1 (96 cols).
// Stage panel once (97.5 KB, rows padded to 520 ushorts -> 2-way banks),
// one barrier, then each wave independently processes 16-row strips:
// per step 2 global A loads (pipelined 1 ahead, named regs) + 6 ds_read_b128
// + 6 MFMA. No barriers/waitcnt in the loop -> free compiler pipelining +
// 4 independent waves/SIMD hide latency.
// ---------------------------------------------------------------------------
__global__ __launch_bounds__(1024, 1) void k1_mfma(
    const float* __restrict__ x, const unsigned short* __restrict__ Bt,
    unsigned short* __restrict__ xw01, float* __restrict__ aggH)
{
    __shared__ unsigned short Bs[96 * BROW];  // 97.5 KB

    const int tid = threadIdx.x;
    const int p = blockIdx.x & 1;

    // stage panel p: 96 rows x 512 ushorts (64 x 16B chunks per row)
    for (int i = tid; i < 96 * 64; i += 1024) {
        const int row = i >> 6, ch = i & 63;
        *(uint4*)&Bs[row * BROW + ch * 8] =
            *(const uint4*)&Bt[(size_t)(p * 96 + row) * KP + ch * 8];
    }
    __syncthreads();

    const int w = tid >> 6;
    const int l = tid & 63;
    const int l16 = l & 15;
    const int koct = l >> 4;  // 0..3

    unsigned* xw01u = (unsigned*)xw01;

    for (int rt = blockIdx.x >> 1; rt < NT; rt += gridDim.x >> 1) {
        const int row0 = rt * 256 + w * 16;
        int arow = row0 + l16;
        if (arow > N_NODES - 1) arow = N_NODES - 1;  // clamp; masked at store
        const float* ap = x + (size_t)arow * IN_DIM + koct * 8;

        f32x4 acc[6];
#pragma unroll
        for (int j = 0; j < 6; ++j) acc[j] = (f32x4){0.f, 0.f, 0.f, 0.f};

        // software pipeline: next-step A in named registers (no dyn indexing)
        float4 nf0 = *(const float4*)(ap);
        float4 nf1 = *(const float4*)(ap + 4);

#pragma unroll
        for (int s = 0; s < NSTEPS; ++s) {
            const float4 f0 = nf0;
            const float4 f1 = nf1;
            if (s + 1 < NSTEPS) {
                const int k0n = (s + 1) * 32;
                if (s + 1 < NSTEPS - 1) {
                    nf0 = *(const float4*)(ap + k0n);
                    nf1 = *(const float4*)(ap + k0n + 4);
                } else {  // last step: k = 480 + koct*8 + j
                    nf0 = (koct <= 2) ? *(const float4*)(ap + k0n)
                                      : make_float4(0.f, 0.f, 0.f, 0.f);
                    nf1 = (koct <= 1) ? *(const float4*)(ap + k0n + 4)
                                      : make_float4(0.f, 0.f, 0.f, 0.f);
                }
            }
            short8 a;
            a[0] = (short)f2bf(f0.x); a[1] = (short)f2bf(f0.y);
            a[2] = (short)f2bf(f0.z); a[3] = (short)f2bf(f0.w);
            a[4] = (short)f2bf(f1.x); a[5] = (short)f2bf(f1.y);
            a[6] = (short)f2bf(f1.z); a[7] = (short)f2bf(f1.w);

            const int kb = s * 32 + koct * 8;
#pragma unroll
            for (int cf = 0; cf < 6; ++cf) {
                short8 bfg = *(const short8*)&Bs[(cf * 16 + l16) * BROW + kb];
                acc[cf] = __builtin_amdgcn_mfma_f32_16x16x32_bf16(a, bfg, acc[cf], 0, 0, 0);
            }
        }

        // epilogue: C row = row0 + koct*4 + reg, fragment col = l16.
        // cf 0,1: xw0 cols p*32+cf*16+l16 (pair with cf+2 = xw1 same col);
        // cf 4,5: root cols p*32+(cf-4)*16+l16 -> aggH.
#pragma unroll
        for (int reg = 0; reg < 4; ++reg) {
            const int r = row0 + koct * 4 + reg;
            if (r < N_NODES) {
#pragma unroll
                for (int cf = 0; cf < 2; ++cf) {
                    const int c = p * 32 + cf * 16 + l16;
                    xw01u[(size_t)r * 64 + c] =
                        pack2(f2bf(acc[cf][reg]), f2bf(acc[cf + 2][reg]));
                }
#pragma unroll
                for (int cf = 4; cf < 6; ++cf) {
                    const int c = p * 32 + (cf - 4) * 16 + l16;
                    aggH[(size_t)r * HID + c] = acc[cf][reg];
                }
            }
        }
    }
}

// ---------------------------------------------------------------------------
// AGG1: wave per node; lane = hidden dim. 16 edges in flight.
// ---------------------------------------------------------------------------
__global__ __launch_bounds__(256) void agg1(
    const int* __restrict__ off, const uint2* __restrict__ epk,
    const unsigned* __restrict__ xw01_u, float* __restrict__ aggH)
{
    const int n = blockIdx.x * 4 + (threadIdx.x >> 6);
    if (n >= N_NODES) return;
    const int d = threadIdx.x & 63;
    const int start = off[n];
    const int deg = off[n + 1] - start;

    float acc = aggH[(size_t)n * HID + d];
    for (int i = 0; i < deg; i += 16) {
        unsigned srcs[16];
        float w0[16], w1[16];
#pragma unroll
        for (int j = 0; j < 16; ++j) {
            const bool ok = (i + j) < deg;
            const int idx = ok ? (start + i + j) : start;
            const uint2 t = epk[idx];
            const float v = __builtin_bit_cast(float, t.y);
            srcs[j] = t.x;
            w0[j] = ok ? (1.f - v) : 0.f;
            w1[j] = ok ? v : 0.f;
        }
        unsigned g[16];
#pragma unroll
        for (int j = 0; j < 16; ++j) g[j] = xw01_u[(size_t)srcs[j] * 64 + d];
#pragma unroll
        for (int j = 0; j < 16; ++j) {
            acc += w0[j] * bf2f((unsigned short)(g[j] & 0xFFFF));
            acc += w1[j] * bf2f((unsigned short)(g[j] >> 16));
        }
    }
    aggH[(size_t)n * HID + d] = acc;
}

// ---------------------------------------------------------------------------
// K3: h = relu(aggH + b1); hw01 = packed bf16 {h@w2[0], h@w2[1]}; agg2 = h@root2.
// ---------------------------------------------------------------------------
__global__ __launch_bounds__(256) void k3_relu_gemm(
    const float* __restrict__ aggH, const float* __restrict__ b1,
    const float* __restrict__ w2, const float* __restrict__ root2,
    unsigned* __restrict__ hw01_u, float* __restrict__ agg2)
{
    __shared__ float Ws[3 * HID * NCLS];
    __shared__ float Hs[16][HID];

    const int tid = threadIdx.x;
    for (int i = tid; i < 2 * HID * NCLS; i += 256) Ws[i] = w2[i];
    for (int i = tid; i < HID * NCLS; i += 256) Ws[2 * HID * NCLS + i] = root2[i];

    const int n0 = blockIdx.x * 16;
    for (int i = tid; i < 16 * HID; i += 256) {
        const int nl = i >> 6, k = i & 63;
        const float h = aggH[(size_t)(n0 + nl) * HID + k] + b1[k];
        Hs[nl][k] = fmaxf(h, 0.f);
    }
    __syncthreads();

    const int nl = tid >> 4;
    const int c = tid & 15;
    float a0 = 0.f, a1 = 0.f, a2 = 0.f;
#pragma unroll
    for (int k = 0; k < HID; ++k) {
        const float h = Hs[nl][k];
        a0 += h * Ws[0 * HID * NCLS + k * NCLS + c];
        a1 += h * Ws[1 * HID * NCLS + k * NCLS + c];
        a2 += h * Ws[2 * HID * NCLS + k * NCLS + c];
    }
    const size_t o = (size_t)(n0 + nl) * NCLS + c;
    hw01_u[o] = pack2(f2bf(a0), f2bf(a1));
    agg2[o] = a2;
}

// ---------------------------------------------------------------------------
// AGG2 + log_softmax fused: 16 lanes per node, 16 nodes per block.
// 16 edges in flight.
// ---------------------------------------------------------------------------
__global__ __launch_bounds__(256) void agg2_sm(
    const int* __restrict__ off, const uint2* __restrict__ epk,
    const unsigned* __restrict__ hw01_u, const float* __restrict__ agg2,
    const float* __restrict__ b2, float* __restrict__ out)
{
    const int n = blockIdx.x * 16 + (threadIdx.x >> 4);
    const int c = threadIdx.x & 15;
    const int start = off[n];
    const int deg = off[n + 1] - start;

    float acc = agg2[(size_t)n * NCLS + c];
    for (int i = 0; i < deg; i += 16) {
        unsigned srcs[16];
        float w0[16], w1[16];
#pragma unroll
        for (int j = 0; j < 16; ++j) {
            const bool ok = (i + j) < deg;
            const int idx = ok ? (start + i + j) : start;
            const uint2 t = epk[idx];
            const float v = __builtin_bit_cast(float, t.y);
            srcs[j] = t.x;
            w0[j] = ok ? (1.f - v) : 0.f;
            w1[j] = ok ? v : 0.f;
        }
        unsigned g[16];
#pragma unroll
        for (int j = 0; j < 16; ++j) g[j] = hw01_u[(size_t)srcs[j] * NCLS + c];
#pragma unroll
        for (int j = 0; j < 16; ++j) {
            acc += w0[j] * bf2f((unsigned short)(g[j] & 0xFFFF));
            acc += w1[j] * bf2f((unsigned short)(g[j] >> 16));
        }
    }

    const float z = acc + b2[c];
    float m = z;
#pragma unroll
    for (int s = 1; s < 16; s <<= 1) m = fmaxf(m, __shfl_xor(m, s, 64));
    const float e = expf(z - m);
    float ssum = e;
#pragma unroll
    for (int s = 1; s < 16; s <<= 1) ssum += __shfl_xor(ssum, s, 64);
    out[(size_t)n * NCLS + c] = (z - m) - logf(ssum);
}

extern "C" void kernel_launch(void* const* d_in, const int* in_sizes, int n_in,
                              void* d_out, int out_size, void* d_ws, size_t ws_size,
                              hipStream_t stream) {
    const float* x = (const float*)d_in[0];
    const int* ei = (const int*)d_in[1];
    const float* ea = (const float*)d_in[2];
    const float* w1 = (const float*)d_in[3];
    const float* root1 = (const float*)d_in[4];
    const float* b1 = (const float*)d_in[5];
    const float* w2 = (const float*)d_in[6];
    const float* root2 = (const float*)d_in[7];
    const float* b2 = (const float*)d_in[8];
    float* out = (float*)d_out;

    char* ws = (char*)d_ws;
    unsigned short* xw01 = (unsigned short*)ws;                 // 25.6 MB
    float* aggH = (float*)(ws + 25600000);                      // 25.6 MB
    unsigned* hw01_u = (unsigned*)(ws + 51200000);              // 6.4 MB
    float* agg2 = (float*)(ws + 57600000);                      // 6.4 MB
    unsigned short* Bt = (unsigned short*)(ws + 64000000);      // 0.2 MB
    int* off = (int*)(ws + 64300000);                           // 0.4 MB (NPAD ints)
    int* bkcnt = (int*)(ws + 64750000);                         // 1.6 KB
    int* bkoff = (int*)(ws + 64760000);                         // 1.6 KB
    int* bkcur = (int*)(ws + 64770000);                         // 1.6 KB
    uint2* epk = (uint2*)(ws + 64800000);                       // 12.8 MB
    uint2* epkS = (uint2*)(ws + 77600000);                      // 12.8 MB -> ~90.4 MB

    // CSR build (bucket-level histogram; per-dst offsets from csr_place)
    csr_bzero<<<1, 512, 0, stream>>>(bkcnt);
    csr_bhist<<<(N_EDGES + EPB - 1) / EPB, 512, 0, stream>>>(ei, bkcnt);
    csr_bscan<<<1, 512, 0, stream>>>(bkcnt, bkoff, bkcur);
    csr_bucket<<<(N_EDGES + EPB - 1) / EPB, 512, 0, stream>>>(ei, ea, bkcur, epk);
    csr_place<<<NBUK, 256, 0, stream>>>(bkoff, epk, epkS, off);

    // layer 1
    k0_bt<<<192, 256, 0, stream>>>(w1, root1, Bt);
    k1_mfma<<<512, 1024, 0, stream>>>(x, Bt, xw01, aggH);
    agg1<<<(N_NODES + 3) / 4, 256, 0, stream>>>(off, epkS, (const unsigned*)xw01, aggH);

    // layer 2
    k3_relu_gemm<<<N_NODES / 16, 256, 0, stream>>>(aggH, b1, w2, root2, hw01_u, agg2);
    agg2_sm<<<N_NODES / 16, 256, 0, stream>>>(off, epkS, hw01_u, agg2, b2, out);
}

// Round 15
// 332.322 us; speedup vs baseline: 2.2291x; 2.2291x over previous
//
#include <hip/hip_runtime.h>
#include <math.h>

#define N_NODES 100000
#define N_EDGES 1600000
#define IN_DIM 500
#define HID 64
#define NCLS 16
#define KP 512     // padded K for layer-1 GEMM
#define NSTEPS 16  // KP/32
#define NBUK 391     // buckets of 256 dsts: bucket = dst >> 8
#define NPAD (NBUK * 256)
#define EPB 8192     // edges per bucket-phase block (512 threads)

typedef __attribute__((ext_vector_type(8))) short short8;
typedef __attribute__((ext_vector_type(4))) float f32x4;

__device__ __forceinline__ unsigned short f2bf(float f) {
    unsigned u = __builtin_bit_cast(unsigned, f);
    return (unsigned short)((u + 0x7FFFu + ((u >> 16) & 1u)) >> 16);
}
__device__ __forceinline__ float bf2f(unsigned short s) {
    unsigned u = ((unsigned)s) << 16;
    return __builtin_bit_cast(float, u);
}
__device__ __forceinline__ unsigned pack2(unsigned short a, unsigned short b) {
    return (unsigned)a | ((unsigned)b << 16);
}
// async global->LDS, 16B per lane; LDS dest is wave-uniform base + lane*16
__device__ __forceinline__ void gload16(const void* g, void* l) {
    __builtin_amdgcn_global_load_lds(
        (const __attribute__((address_space(1))) unsigned*)g,
        (__attribute__((address_space(3))) unsigned*)l, 16, 0, 0);
}

// ---------------------------------------------------------------------------
// K0: build Bt[192][512] bf16 = transpose of {w1[0], w1[1], root1}, zero-pad K.
// ---------------------------------------------------------------------------
__global__ __launch_bounds__(256) void k0_bt(
    const float* __restrict__ w1, const float* __restrict__ root1,
    unsigned short* __restrict__ Bt)
{
    const int b = blockIdx.x;  // 0..191
    const float* src;
    int c;
    if (b < 64)        { src = w1;                c = b; }
    else if (b < 128)  { src = w1 + IN_DIM * HID; c = b - 64; }
    else               { src = root1;             c = b - 128; }
    for (int k = threadIdx.x; k < KP; k += 256) {
        float v = (k < IN_DIM) ? src[k * HID + c] : 0.f;
        Bt[b * KP + k] = f2bf(v);
    }
}

// ---------------------------------------------------------------------------
// CSR build, bucket-level.
// ---------------------------------------------------------------------------
__global__ __launch_bounds__(512) void csr_bzero(int* __restrict__ bkcnt)
{
    if (threadIdx.x < NBUK) bkcnt[threadIdx.x] = 0;
}

__global__ __launch_bounds__(512) void csr_bhist(
    const int* __restrict__ ei, int* __restrict__ bkcnt)
{
    __shared__ int h[NBUK];
    const int tid = threadIdx.x;
    for (int i = tid; i < NBUK; i += 512) h[i] = 0;
    __syncthreads();
    const int start = blockIdx.x * EPB;
    const int eend = min(start + EPB, N_EDGES);
#pragma unroll
    for (int j = 0; j < EPB / 512; ++j) {
        const int e = start + j * 512 + tid;
        if (e < eend) atomicAdd(&h[ei[N_EDGES + e] >> 8], 1);
    }
    __syncthreads();
    for (int i = tid; i < NBUK; i += 512)
        if (h[i]) atomicAdd(&bkcnt[i], h[i]);
}

__global__ __launch_bounds__(512) void csr_bscan(
    const int* __restrict__ bkcnt, int* __restrict__ bkoff, int* __restrict__ bkcur)
{
    __shared__ int s[512];
    const int t = threadIdx.x;
    const int val = (t < NBUK) ? bkcnt[t] : 0;
    s[t] = val;
    for (int d = 1; d < 512; d <<= 1) {
        __syncthreads();
        int add = (t >= d) ? s[t - d] : 0;
        __syncthreads();
        s[t] += add;
    }
    __syncthreads();
    if (t < NBUK) {
        const int o = s[t] - val;
        bkoff[t] = o;
        bkcur[t] = o;
    }
    if (t == NBUK - 1) bkoff[NBUK] = s[t];  // == N_EDGES
}

// Phase 1: scatter edges into their 256-dst bucket region.
// Record: x = src, y = (dstlow<<24) | v_fixed24.
__global__ __launch_bounds__(512) void csr_bucket(
    const int* __restrict__ ei, const float* __restrict__ ea,
    int* __restrict__ bkcur, uint2* __restrict__ epk)
{
    __shared__ int hcnt[NBUK];
    __shared__ int hbase[NBUK];

    const int tid = threadIdx.x;
    const int start = blockIdx.x * EPB;
    const int eend = min(start + EPB, N_EDGES);

    for (int i = tid; i < NBUK; i += 512) hcnt[i] = 0;
    __syncthreads();

#pragma unroll
    for (int j = 0; j < EPB / 512; ++j) {
        const int e = start + j * 512 + tid;
        if (e < eend) atomicAdd(&hcnt[ei[N_EDGES + e] >> 8], 1);
    }
    __syncthreads();

    for (int b = tid; b < NBUK; b += 512) {
        const int c = hcnt[b];
        hbase[b] = c ? atomicAdd(&bkcur[b], c) : 0;
    }
    __syncthreads();
    for (int i = tid; i < NBUK; i += 512) hcnt[i] = 0;
    __syncthreads();

#pragma unroll
    for (int j = 0; j < EPB / 512; ++j) {
        const int e = start + j * 512 + tid;
        if (e < eend) {
            const int src = ei[e];
            const int dst = ei[N_EDGES + e];
            const float v = fminf(fmaxf(ea[e], 0.f), 1.f - 1e-6f);
            const unsigned vq = (unsigned)(v * 16777216.0f);  // 24-bit fixed
            const int bk = dst >> 8;
            const int r = atomicAdd(&hcnt[bk], 1);
            epk[hbase[bk] + r] =
                make_uint2((unsigned)src, ((unsigned)(dst & 255) << 24) | vq);
        }
    }
}

// Phase 2: per bucket, 2-pass: (a) LDS hist of 256 dsts + LDS scan -> global
// off[]; (b) re-read records, rank via LDS atomics, write (src, v_f32) to epkS.
__global__ __launch_bounds__(256) void csr_place(
    const int* __restrict__ bkoff, const uint2* __restrict__ epk,
    uint2* __restrict__ epkS, int* __restrict__ off)
{
    __shared__ int hist[256];
    __shared__ int sc[256];
    __shared__ int cur[256];

    const int b = blockIdx.x;
    const int tid = threadIdx.x;
    const int start = bkoff[b];
    const int end = bkoff[b + 1];
    const int cnt = end - start;

    hist[tid] = 0;
    __syncthreads();
    for (int i = tid; i < cnt; i += 256)
        atomicAdd(&hist[epk[start + i].y >> 24], 1);
    __syncthreads();

    const int val = hist[tid];
    sc[tid] = val;
    for (int d = 1; d < 256; d <<= 1) {
        __syncthreads();
        int add = (tid >= d) ? sc[tid - d] : 0;
        __syncthreads();
        sc[tid] += add;
    }
    __syncthreads();
    const int mystart = start + sc[tid] - val;  // exclusive
    off[(b << 8) + tid] = mystart;
    cur[tid] = mystart;
    __syncthreads();

    for (int i = tid; i < cnt; i += 256) {
        const uint2 u = epk[start + i];
        const int dl = u.y >> 24;
        const float v = (float)(u.y & 0xFFFFFFu) * 5.9604644775390625e-8f;
        const int pos = atomicAdd(&cur[dl], 1);
        epkS[pos] = make_uint2(u.x, __builtin_bit_cast(unsigned, v));
    }
}

// ---------------------------------------------------------------------------
// K1: bf16 MFMA GEMM (R11's proven 111us variant). global_load_lds staging,
// 4 LDS buffers, depth-3 prefetch, counted vmcnt, wait->barrier->issue order.
// Tile: 64 rows x 192 cols, BK=32. 4 waves in 2x2.
// ---------------------------------------------------------------------------
union K1Smem {
    struct { float A[4][64 * 32]; unsigned short B[4][192 * 32]; } s;  // 80KB
    unsigned short O[64 * 264];  // epilogue staging (33.8 KB)
};

__global__ __launch_bounds__(256) void k1_mfma(
    const float* __restrict__ x, const unsigned short* __restrict__ Bt,
    unsigned short* __restrict__ xw01, float* __restrict__ aggH)
{
    __shared__ K1Smem sm;

    const int tid = threadIdx.x;
    const int row0 = blockIdx.x * 64;
    const int w = tid >> 6;
    const int l = tid & 63;
    const int l16 = l & 15;
    const int koct = l >> 4;
    const int wr = w >> 1;
    const int wc = w & 1;

    f32x4 acc[2][6];
#pragma unroll
    for (int i = 0; i < 2; ++i)
#pragma unroll
        for (int j = 0; j < 6; ++j) acc[i][j] = (f32x4){0.f, 0.f, 0.f, 0.f};

    const int aChunk4 = (l & 7) * 4;
    const float* aBase[2];
    int aLdsOff[2];
#pragma unroll
    for (int i = 0; i < 2; ++i) {
        const int rowl = (2 * w + i) * 8 + (l >> 3);
        int grow = row0 + rowl;
        if (grow > N_NODES - 1) grow = N_NODES - 1;
        aBase[i] = x + (size_t)grow * IN_DIM;
        aLdsOff[i] = (2 * w + i) * 256;  // floats
    }
    const unsigned short* bBase[3];
    int bLdsOff[3];
#pragma unroll
    for (int i = 0; i < 3; ++i) {
        const int coll = (3 * w + i) * 16 + (l >> 2);
        bBase[i] = Bt + (size_t)coll * KP + (l & 3) * 8;
        bLdsOff[i] = (3 * w + i) * 512;  // ushorts
    }

    auto ISSUE = [&](int s) {
        const int k0 = s * 32;
        const int buf = s & 3;
#pragma unroll
        for (int i = 0; i < 2; ++i) {
            int gk = k0 + aChunk4; if (gk > IN_DIM - 4) gk = IN_DIM - 4;
            gload16(aBase[i] + gk, &sm.s.A[buf][aLdsOff[i]]);
        }
#pragma unroll
        for (int i = 0; i < 3; ++i)
            gload16(bBase[i] + k0, &sm.s.B[buf][bLdsOff[i]]);
    };

    ISSUE(0);
    ISSUE(1);
    ISSUE(2);

#pragma unroll
    for (int s = 0; s < NSTEPS; ++s) {
        if (s < NSTEPS - 2)       asm volatile("s_waitcnt vmcnt(10)" ::: "memory");
        else if (s == NSTEPS - 2) asm volatile("s_waitcnt vmcnt(5)" ::: "memory");
        else                      asm volatile("s_waitcnt vmcnt(0)" ::: "memory");
        __builtin_amdgcn_s_barrier();
        asm volatile("" ::: "memory");
        if (s + 3 < NSTEPS) ISSUE(s + 3);

        const int buf = s & 3;
        const float* LA = sm.s.A[buf];
        const unsigned short* LB = sm.s.B[buf];
        short8 af[2];
#pragma unroll
        for (int rb = 0; rb < 2; ++rb) {
            const int r = wr * 32 + rb * 16 + l16;
            f32x4 f0 = *(const f32x4*)&LA[r * 32 + koct * 8];
            f32x4 f1 = *(const f32x4*)&LA[r * 32 + koct * 8 + 4];
            short8 a;
            a[0] = (short)f2bf(f0[0]); a[1] = (short)f2bf(f0[1]);
            a[2] = (short)f2bf(f0[2]); a[3] = (short)f2bf(f0[3]);
            a[4] = (short)f2bf(f1[0]); a[5] = (short)f2bf(f1[1]);
            a[6] = (short)f2bf(f1[2]); a[7] = (short)f2bf(f1[3]);
            af[rb] = a;
        }
#pragma unroll
        for (int cf = 0; cf < 6; ++cf) {
            const int c = wc * 96 + cf * 16 + l16;
            short8 bfg = *(const short8*)&LB[c * 32 + koct * 8];
            acc[0][cf] = __builtin_amdgcn_mfma_f32_16x16x32_bf16(af[0], bfg, acc[0][cf], 0, 0, 0);
            acc[1][cf] = __builtin_amdgcn_mfma_f32_16x16x32_bf16(af[1], bfg, acc[1][cf], 0, 0, 0);
        }
    }
    __syncthreads();

#pragma unroll
    for (int rb = 0; rb < 2; ++rb)
#pragma unroll
        for (int cf = 0; cf < 6; ++cf) {
            const int cg = wc * 96 + cf * 16 + l16;
            if (96 * wc + cf * 16 < 128) {
#pragma unroll
                for (int reg = 0; reg < 4; ++reg) {
                    const int rloc = wr * 32 + rb * 16 + koct * 4 + reg;
                    const int idx = (cg < 64) ? (2 * cg) : (2 * cg - 127);
                    sm.O[rloc * 264 + idx] = f2bf(acc[rb][cf][reg]);
                }
            } else {
#pragma unroll
                for (int reg = 0; reg < 4; ++reg) {
                    const int r = row0 + wr * 32 + rb * 16 + koct * 4 + reg;
                    if (r < N_NODES) aggH[(size_t)r * HID + (cg - 128)] = acc[rb][cf][reg];
                }
            }
        }
    __syncthreads();
    {
        const int row = tid >> 2, q = tid & 3;
        const int rg = row0 + row;
        if (rg < N_NODES) {
#pragma unroll
            for (int j = 0; j < 4; ++j) {
                uint4 v = *(const uint4*)&sm.O[row * 264 + q * 32 + j * 8];
                *(uint4*)&xw01[(size_t)rg * 128 + q * 32 + j * 8] = v;
            }
        }
    }
}

// ---------------------------------------------------------------------------
// AGG1K3 (fused agg1 + k3): wave per node; lane = hidden dim. 16 edges in
// flight. Then in-wave: h = relu(acc + b1); GEMV vs {w2[0], w2[1], root2}
// via 64 __shfl broadcasts (weights staged in 12 KB LDS). Writes hw01_u +
// agg2 only — aggH is no longer written back (saves 51 MB round trip + a
// kernel launch).
// ---------------------------------------------------------------------------
__global__ __launch_bounds__(256) void agg1k3(
    const int* __restrict__ off, const uint2* __restrict__ epk,
    const unsigned* __restrict__ xw01_u, const float* __restrict__ aggH,
    const float* __restrict__ b1, const float* __restrict__ w2,
    const float* __restrict__ root2, unsigned* __restrict__ hw01_u,
    float* __restrict__ agg2)
{
    __shared__ float Ws[3 * HID * NCLS];  // 12 KB: w2[0], w2[1], root2

    const int tid = threadIdx.x;
    for (int i = tid; i < 2 * HID * NCLS; i += 256) Ws[i] = w2[i];
    for (int i = tid; i < HID * NCLS; i += 256) Ws[2 * HID * NCLS + i] = root2[i];
    __syncthreads();

    const int n = blockIdx.x * 4 + (tid >> 6);
    const int d = tid & 63;
    const int start = off[n];
    const int deg = off[n + 1] - start;

    float acc = aggH[(size_t)n * HID + d];
    for (int i = 0; i < deg; i += 16) {
        unsigned srcs[16];
        float w0[16], w1[16];
#pragma unroll
        for (int j = 0; j < 16; ++j) {
            const bool ok = (i + j) < deg;
            const int idx = ok ? (start + i + j) : start;
            const uint2 t = epk[idx];
            const float v = __builtin_bit_cast(float, t.y);
            srcs[j] = t.x;
            w0[j] = ok ? (1.f - v) : 0.f;
            w1[j] = ok ? v : 0.f;
        }
        unsigned g[16];
#pragma unroll
        for (int j = 0; j < 16; ++j) g[j] = xw01_u[(size_t)srcs[j] * 64 + d];
#pragma unroll
        for (int j = 0; j < 16; ++j) {
            acc += w0[j] * bf2f((unsigned short)(g[j] & 0xFFFF));
            acc += w1[j] * bf2f((unsigned short)(g[j] >> 16));
        }
    }

    // --- fused k3: h = relu(acc + b1[d]); per-wave GEMV via shfl broadcast ---
    const float h = fmaxf(acc + b1[d], 0.f);
    const int c = d & 15;
    const int m = d >> 4;            // 0: w2[0], 1: w2[1], 2: root2, 3: dup
    const int mm = (m < 3) ? m : 2;  // clamp to stay in Ws bounds
    float a = 0.f;
#pragma unroll
    for (int k = 0; k < HID; ++k) {
        const float hv = __shfl(h, k, 64);
        a += hv * Ws[mm * HID * NCLS + k * NCLS + c];
    }
    const float a1v = __shfl(a, 16 + c, 64);  // w2[1] result for this class
    if (m == 0) hw01_u[(size_t)n * NCLS + c] = pack2(f2bf(a), f2bf(a1v));
    else if (m == 2) agg2[(size_t)n * NCLS + c] = a;
}

// ---------------------------------------------------------------------------
// AGG2 + log_softmax fused: 16 lanes per node, 16 nodes per block.
// 16 edges in flight.
// ---------------------------------------------------------------------------
__global__ __launch_bounds__(256) void agg2_sm(
    const int* __restrict__ off, const uint2* __restrict__ epk,
    const unsigned* __restrict__ hw01_u, const float* __restrict__ agg2,
    const float* __restrict__ b2, float* __restrict__ out)
{
    const int n = blockIdx.x * 16 + (threadIdx.x >> 4);
    const int c = threadIdx.x & 15;
    const int start = off[n];
    const int deg = off[n + 1] - start;

    float acc = agg2[(size_t)n * NCLS + c];
    for (int i = 0; i < deg; i += 16) {
        unsigned srcs[16];
        float w0[16], w1[16];
#pragma unroll
        for (int j = 0; j < 16; ++j) {
            const bool ok = (i + j) < deg;
            const int idx = ok ? (start + i + j) : start;
            const uint2 t = epk[idx];
            const float v = __builtin_bit_cast(float, t.y);
            srcs[j] = t.x;
            w0[j] = ok ? (1.f - v) : 0.f;
            w1[j] = ok ? v : 0.f;
        }
        unsigned g[16];
#pragma unroll
        for (int j = 0; j < 16; ++j) g[j] = hw01_u[(size_t)srcs[j] * NCLS + c];
#pragma unroll
        for (int j = 0; j < 16; ++j) {
            acc += w0[j] * bf2f((unsigned short)(g[j] & 0xFFFF));
            acc += w1[j] * bf2f((unsigned short)(g[j] >> 16));
        }
    }

    const float z = acc + b2[c];
    float m = z;
#pragma unroll
    for (int s = 1; s < 16; s <<= 1) m = fmaxf(m, __shfl_xor(m, s, 64));
    const float e = expf(z - m);
    float ssum = e;
#pragma unroll
    for (int s = 1; s < 16; s <<= 1) ssum += __shfl_xor(ssum, s, 64);
    out[(size_t)n * NCLS + c] = (z - m) - logf(ssum);
}

extern "C" void kernel_launch(void* const* d_in, const int* in_sizes, int n_in,
                              void* d_out, int out_size, void* d_ws, size_t ws_size,
                              hipStream_t stream) {
    const float* x = (const float*)d_in[0];
    const int* ei = (const int*)d_in[1];
    const float* ea = (const float*)d_in[2];
    const float* w1 = (const float*)d_in[3];
    const float* root1 = (const float*)d_in[4];
    const float* b1 = (const float*)d_in[5];
    const float* w2 = (const float*)d_in[6];
    const float* root2 = (const float*)d_in[7];
    const float* b2 = (const float*)d_in[8];
    float* out = (float*)d_out;

    char* ws = (char*)d_ws;
    unsigned short* xw01 = (unsigned short*)ws;                 // 25.6 MB
    float* aggH = (float*)(ws + 25600000);                      // 25.6 MB
    unsigned* hw01_u = (unsigned*)(ws + 51200000);              // 6.4 MB
    float* agg2 = (float*)(ws + 57600000);                      // 6.4 MB
    unsigned short* Bt = (unsigned short*)(ws + 64000000);      // 0.2 MB
    int* off = (int*)(ws + 64300000);                           // 0.4 MB (NPAD ints)
    int* bkcnt = (int*)(ws + 64750000);                         // 1.6 KB
    int* bkoff = (int*)(ws + 64760000);                         // 1.6 KB
    int* bkcur = (int*)(ws + 64770000);                         // 1.6 KB
    uint2* epk = (uint2*)(ws + 64800000);                       // 12.8 MB
    uint2* epkS = (uint2*)(ws + 77600000);                      // 12.8 MB -> ~90.4 MB

    // CSR build (bucket-level histogram; per-dst offsets from csr_place)
    csr_bzero<<<1, 512, 0, stream>>>(bkcnt);
    csr_bhist<<<(N_EDGES + EPB - 1) / EPB, 512, 0, stream>>>(ei, bkcnt);
    csr_bscan<<<1, 512, 0, stream>>>(bkcnt, bkoff, bkcur);
    csr_bucket<<<(N_EDGES + EPB - 1) / EPB, 512, 0, stream>>>(ei, ea, bkcur, epk);
    csr_place<<<NBUK, 256, 0, stream>>>(bkoff, epk, epkS, off);

    // layer 1
    k0_bt<<<192, 256, 0, stream>>>(w1, root1, Bt);
    k1_mfma<<<(N_NODES + 63) / 64, 256, 0, stream>>>(x, Bt, xw01, aggH);
    agg1k3<<<N_NODES / 4, 256, 0, stream>>>(off, epkS, (const unsigned*)xw01,
                                            aggH, b1, w2, root2, hw01_u, agg2);

    // layer 2
    agg2_sm<<<N_NODES / 16, 256, 0, stream>>>(off, epkS, hw01_u, agg2, b2, out);
}

// Round 16
// 274.596 us; speedup vs baseline: 2.6977x; 1.2102x over previous
//
#include <hip/hip_runtime.h>
#include <math.h>

#define N_NODES 100000
#define N_EDGES 1600000
#define IN_DIM 500
#define HID 64
#define NCLS 16
#define KP 512     // padded K for layer-1 GEMM
#define NSTEPS 16  // KP/32
#define NBUK 391   // buckets of 256 dsts: bucket = dst >> 8
#define NPAD (NBUK * 256)
#define EPB 8192   // edges per bucket-phase block (512 threads)
#define CAP 8192   // fixed slots per bucket (mean 4096, +64 sigma; ws is ~800MB)

typedef __attribute__((ext_vector_type(8))) short short8;
typedef __attribute__((ext_vector_type(4))) float f32x4;

__device__ __forceinline__ unsigned short f2bf(float f) {
    unsigned u = __builtin_bit_cast(unsigned, f);
    return (unsigned short)((u + 0x7FFFu + ((u >> 16) & 1u)) >> 16);
}
__device__ __forceinline__ float bf2f(unsigned short s) {
    unsigned u = ((unsigned)s) << 16;
    return __builtin_bit_cast(float, u);
}
__device__ __forceinline__ unsigned pack2(unsigned short a, unsigned short b) {
    return (unsigned)a | ((unsigned)b << 16);
}
// async global->LDS, 16B per lane; LDS dest is wave-uniform base + lane*16
__device__ __forceinline__ void gload16(const void* g, void* l) {
    __builtin_amdgcn_global_load_lds(
        (const __attribute__((address_space(1))) unsigned*)g,
        (__attribute__((address_space(3))) unsigned*)l, 16, 0, 0);
}

// ---------------------------------------------------------------------------
// K0: build Bt[192][512] bf16 = transpose of {w1[0], w1[1], root1}, zero-pad K.
// ---------------------------------------------------------------------------
__global__ __launch_bounds__(256) void k0_bt(
    const float* __restrict__ w1, const float* __restrict__ root1,
    unsigned short* __restrict__ Bt)
{
    const int b = blockIdx.x;  // 0..191
    const float* src;
    int c;
    if (b < 64)        { src = w1;                c = b; }
    else if (b < 128)  { src = w1 + IN_DIM * HID; c = b - 64; }
    else               { src = root1;             c = b - 128; }
    for (int k = threadIdx.x; k < KP; k += 256) {
        float v = (k < IN_DIM) ? src[k * HID + c] : 0.f;
        Bt[b * KP + k] = f2bf(v);
    }
}

// ---------------------------------------------------------------------------
// CSR build with FIXED-CAPACITY bucket regions (no global histogram/scan):
//   bzero (bkcur[b] = b*CAP) -> bucket (LDS-aggregated rank scatter) ->
//   place (per-dst offsets within bucket + final sort into epkS; writes
//   off[] = padded global position and deg[]).
// ---------------------------------------------------------------------------
__global__ __launch_bounds__(512) void csr_bzero(int* __restrict__ bkcur)
{
    if (threadIdx.x < NBUK) bkcur[threadIdx.x] = threadIdx.x * CAP;
}

// Phase 1: scatter edges into their 256-dst bucket region.
// Record: x = src, y = (dstlow<<24) | v_fixed24.
__global__ __launch_bounds__(512) void csr_bucket(
    const int* __restrict__ ei, const float* __restrict__ ea,
    int* __restrict__ bkcur, uint2* __restrict__ epk)
{
    __shared__ int hcnt[NBUK];
    __shared__ int hbase[NBUK];

    const int tid = threadIdx.x;
    const int start = blockIdx.x * EPB;
    const int eend = min(start + EPB, N_EDGES);

    for (int i = tid; i < NBUK; i += 512) hcnt[i] = 0;
    __syncthreads();

#pragma unroll
    for (int j = 0; j < EPB / 512; ++j) {
        const int e = start + j * 512 + tid;
        if (e < eend) atomicAdd(&hcnt[ei[N_EDGES + e] >> 8], 1);
    }
    __syncthreads();

    for (int b = tid; b < NBUK; b += 512) {
        const int c = hcnt[b];
        hbase[b] = c ? atomicAdd(&bkcur[b], c) : 0;
    }
    __syncthreads();
    for (int i = tid; i < NBUK; i += 512) hcnt[i] = 0;
    __syncthreads();

#pragma unroll
    for (int j = 0; j < EPB / 512; ++j) {
        const int e = start + j * 512 + tid;
        if (e < eend) {
            const int src = ei[e];
            const int dst = ei[N_EDGES + e];
            const float v = fminf(fmaxf(ea[e], 0.f), 1.f - 1e-6f);
            const unsigned vq = (unsigned)(v * 16777216.0f);  // 24-bit fixed
            const int bk = dst >> 8;
            const int r = atomicAdd(&hcnt[bk], 1);
            epk[hbase[bk] + r] =
                make_uint2((unsigned)src, ((unsigned)(dst & 255) << 24) | vq);
        }
    }
}

// Phase 2: per bucket, 2-pass: (a) LDS hist of 256 dsts + LDS scan -> off[]
// (padded layout: bucket b starts at b*CAP) and deg[]; (b) re-read records,
// rank via LDS atomics, write (src, v_f32) to epkS at off[dst]+rank.
__global__ __launch_bounds__(256) void csr_place(
    const int* __restrict__ bkcur, const uint2* __restrict__ epk,
    uint2* __restrict__ epkS, int* __restrict__ off, int* __restrict__ deg)
{
    __shared__ int hist[256];
    __shared__ int sc[256];
    __shared__ int cur[256];

    const int b = blockIdx.x;
    const int tid = threadIdx.x;
    const int start = b * CAP;
    const int cnt = bkcur[b] - start;

    hist[tid] = 0;
    __syncthreads();
    for (int i = tid; i < cnt; i += 256)
        atomicAdd(&hist[epk[start + i].y >> 24], 1);
    __syncthreads();

    const int val = hist[tid];
    sc[tid] = val;
    for (int d = 1; d < 256; d <<= 1) {
        __syncthreads();
        int add = (tid >= d) ? sc[tid - d] : 0;
        __syncthreads();
        sc[tid] += add;
    }
    __syncthreads();
    const int mystart = start + sc[tid] - val;  // exclusive within bucket
    off[(b << 8) + tid] = mystart;
    deg[(b << 8) + tid] = val;
    cur[tid] = mystart;
    __syncthreads();

    for (int i = tid; i < cnt; i += 256) {
        const uint2 u = epk[start + i];
        const int dl = u.y >> 24;
        const float v = (float)(u.y & 0xFFFFFFu) * 5.9604644775390625e-8f;
        const int pos = atomicAdd(&cur[dl], 1);
        epkS[pos] = make_uint2(u.x, __builtin_bit_cast(unsigned, v));
    }
}

// ---------------------------------------------------------------------------
// K1: bf16 MFMA GEMM (proven 111us variant). global_load_lds staging,
// 4 LDS buffers, depth-3 prefetch, counted vmcnt, wait->barrier->issue order.
// Tile: 64 rows x 192 cols, BK=32. 4 waves in 2x2.
// ---------------------------------------------------------------------------
union K1Smem {
    struct { float A[4][64 * 32]; unsigned short B[4][192 * 32]; } s;  // 80KB
    unsigned short O[64 * 264];  // epilogue staging (33.8 KB)
};

__global__ __launch_bounds__(256) void k1_mfma(
    const float* __restrict__ x, const unsigned short* __restrict__ Bt,
    unsigned short* __restrict__ xw01, float* __restrict__ aggH)
{
    __shared__ K1Smem sm;

    const int tid = threadIdx.x;
    const int row0 = blockIdx.x * 64;
    const int w = tid >> 6;
    const int l = tid & 63;
    const int l16 = l & 15;
    const int koct = l >> 4;
    const int wr = w >> 1;
    const int wc = w & 1;

    f32x4 acc[2][6];
#pragma unroll
    for (int i = 0; i < 2; ++i)
#pragma unroll
        for (int j = 0; j < 6; ++j) acc[i][j] = (f32x4){0.f, 0.f, 0.f, 0.f};

    const int aChunk4 = (l & 7) * 4;
    const float* aBase[2];
    int aLdsOff[2];
#pragma unroll
    for (int i = 0; i < 2; ++i) {
        const int rowl = (2 * w + i) * 8 + (l >> 3);
        int grow = row0 + rowl;
        if (grow > N_NODES - 1) grow = N_NODES - 1;
        aBase[i] = x + (size_t)grow * IN_DIM;
        aLdsOff[i] = (2 * w + i) * 256;  // floats
    }
    const unsigned short* bBase[3];
    int bLdsOff[3];
#pragma unroll
    for (int i = 0; i < 3; ++i) {
        const int coll = (3 * w + i) * 16 + (l >> 2);
        bBase[i] = Bt + (size_t)coll * KP + (l & 3) * 8;
        bLdsOff[i] = (3 * w + i) * 512;  // ushorts
    }

    auto ISSUE = [&](int s) {
        const int k0 = s * 32;
        const int buf = s & 3;
#pragma unroll
        for (int i = 0; i < 2; ++i) {
            int gk = k0 + aChunk4; if (gk > IN_DIM - 4) gk = IN_DIM - 4;
            gload16(aBase[i] + gk, &sm.s.A[buf][aLdsOff[i]]);
        }
#pragma unroll
        for (int i = 0; i < 3; ++i)
            gload16(bBase[i] + k0, &sm.s.B[buf][bLdsOff[i]]);
    };

    ISSUE(0);
    ISSUE(1);
    ISSUE(2);

#pragma unroll
    for (int s = 0; s < NSTEPS; ++s) {
        if (s < NSTEPS - 2)       asm volatile("s_waitcnt vmcnt(10)" ::: "memory");
        else if (s == NSTEPS - 2) asm volatile("s_waitcnt vmcnt(5)" ::: "memory");
        else                      asm volatile("s_waitcnt vmcnt(0)" ::: "memory");
        __builtin_amdgcn_s_barrier();
        asm volatile("" ::: "memory");
        if (s + 3 < NSTEPS) ISSUE(s + 3);

        const int buf = s & 3;
        const float* LA = sm.s.A[buf];
        const unsigned short* LB = sm.s.B[buf];
        short8 af[2];
#pragma unroll
        for (int rb = 0; rb < 2; ++rb) {
            const int r = wr * 32 + rb * 16 + l16;
            f32x4 f0 = *(const f32x4*)&LA[r * 32 + koct * 8];
            f32x4 f1 = *(const f32x4*)&LA[r * 32 + koct * 8 + 4];
            short8 a;
            a[0] = (short)f2bf(f0[0]); a[1] = (short)f2bf(f0[1]);
            a[2] = (short)f2bf(f0[2]); a[3] = (short)f2bf(f0[3]);
            a[4] = (short)f2bf(f1[0]); a[5] = (short)f2bf(f1[1]);
            a[6] = (short)f2bf(f1[2]); a[7] = (short)f2bf(f1[3]);
            af[rb] = a;
        }
#pragma unroll
        for (int cf = 0; cf < 6; ++cf) {
            const int c = wc * 96 + cf * 16 + l16;
            short8 bfg = *(const short8*)&LB[c * 32 + koct * 8];
            acc[0][cf] = __builtin_amdgcn_mfma_f32_16x16x32_bf16(af[0], bfg, acc[0][cf], 0, 0, 0);
            acc[1][cf] = __builtin_amdgcn_mfma_f32_16x16x32_bf16(af[1], bfg, acc[1][cf], 0, 0, 0);
        }
    }
    __syncthreads();

#pragma unroll
    for (int rb = 0; rb < 2; ++rb)
#pragma unroll
        for (int cf = 0; cf < 6; ++cf) {
            const int cg = wc * 96 + cf * 16 + l16;
            if (96 * wc + cf * 16 < 128) {
#pragma unroll
                for (int reg = 0; reg < 4; ++reg) {
                    const int rloc = wr * 32 + rb * 16 + koct * 4 + reg;
                    const int idx = (cg < 64) ? (2 * cg) : (2 * cg - 127);
                    sm.O[rloc * 264 + idx] = f2bf(acc[rb][cf][reg]);
                }
            } else {
#pragma unroll
                for (int reg = 0; reg < 4; ++reg) {
                    const int r = row0 + wr * 32 + rb * 16 + koct * 4 + reg;
                    if (r < N_NODES) aggH[(size_t)r * HID + (cg - 128)] = acc[rb][cf][reg];
                }
            }
        }
    __syncthreads();
    {
        const int row = tid >> 2, q = tid & 3;
        const int rg = row0 + row;
        if (rg < N_NODES) {
#pragma unroll
            for (int j = 0; j < 4; ++j) {
                uint4 v = *(const uint4*)&sm.O[row * 264 + q * 32 + j * 8];
                *(uint4*)&xw01[(size_t)rg * 128 + q * 32 + j * 8] = v;
            }
        }
    }
}

// ---------------------------------------------------------------------------
// AGG1: wave per node; lane = hidden dim. 8 edges in flight.
// ---------------------------------------------------------------------------
__global__ __launch_bounds__(256) void agg1(
    const int* __restrict__ off, const int* __restrict__ deg,
    const uint2* __restrict__ epk, const unsigned* __restrict__ xw01_u,
    float* __restrict__ aggH)
{
    const int n = blockIdx.x * 4 + (threadIdx.x >> 6);
    if (n >= N_NODES) return;
    const int d = threadIdx.x & 63;
    const int start = off[n];
    const int dg = deg[n];

    float acc = aggH[(size_t)n * HID + d];
    for (int i = 0; i < dg; i += 8) {
        unsigned srcs[8];
        float w0[8], w1[8];
#pragma unroll
        for (int j = 0; j < 8; ++j) {
            const bool ok = (i + j) < dg;
            const int idx = ok ? (start + i + j) : start;
            const uint2 t = epk[idx];
            const float v = __builtin_bit_cast(float, t.y);
            srcs[j] = t.x;
            w0[j] = ok ? (1.f - v) : 0.f;
            w1[j] = ok ? v : 0.f;
        }
        unsigned g[8];
#pragma unroll
        for (int j = 0; j < 8; ++j) g[j] = xw01_u[(size_t)srcs[j] * 64 + d];
#pragma unroll
        for (int j = 0; j < 8; ++j) {
            acc += w0[j] * bf2f((unsigned short)(g[j] & 0xFFFF));
            acc += w1[j] * bf2f((unsigned short)(g[j] >> 16));
        }
    }
    aggH[(size_t)n * HID + d] = acc;
}

// ---------------------------------------------------------------------------
// K3: h = relu(aggH + b1); hw01 = packed bf16 {h@w2[0], h@w2[1]}; agg2 = h@root2.
// ---------------------------------------------------------------------------
__global__ __launch_bounds__(256) void k3_relu_gemm(
    const float* __restrict__ aggH, const float* __restrict__ b1,
    const float* __restrict__ w2, const float* __restrict__ root2,
    unsigned* __restrict__ hw01_u, float* __restrict__ agg2)
{
    __shared__ float Ws[3 * HID * NCLS];
    __shared__ float Hs[16][HID];

    const int tid = threadIdx.x;
    for (int i = tid; i < 2 * HID * NCLS; i += 256) Ws[i] = w2[i];
    for (int i = tid; i < HID * NCLS; i += 256) Ws[2 * HID * NCLS + i] = root2[i];

    const int n0 = blockIdx.x * 16;
    for (int i = tid; i < 16 * HID; i += 256) {
        const int nl = i >> 6, k = i & 63;
        const float h = aggH[(size_t)(n0 + nl) * HID + k] + b1[k];
        Hs[nl][k] = fmaxf(h, 0.f);
    }
    __syncthreads();

    const int nl = tid >> 4;
    const int c = tid & 15;
    float a0 = 0.f, a1 = 0.f, a2 = 0.f;
#pragma unroll
    for (int k = 0; k < HID; ++k) {
        const float h = Hs[nl][k];
        a0 += h * Ws[0 * HID * NCLS + k * NCLS + c];
        a1 += h * Ws[1 * HID * NCLS + k * NCLS + c];
        a2 += h * Ws[2 * HID * NCLS + k * NCLS + c];
    }
    const size_t o = (size_t)(n0 + nl) * NCLS + c;
    hw01_u[o] = pack2(f2bf(a0), f2bf(a1));
    agg2[o] = a2;
}

// ---------------------------------------------------------------------------
// AGG2 + log_softmax fused: 16 lanes per node, 16 nodes per block.
// 8 edges in flight.
// ---------------------------------------------------------------------------
__global__ __launch_bounds__(256) void agg2_sm(
    const int* __restrict__ off, const int* __restrict__ deg,
    const uint2* __restrict__ epk, const unsigned* __restrict__ hw01_u,
    const float* __restrict__ agg2, const float* __restrict__ b2,
    float* __restrict__ out)
{
    const int n = blockIdx.x * 16 + (threadIdx.x >> 4);
    const int c = threadIdx.x & 15;
    const int start = off[n];
    const int dg = deg[n];

    float acc = agg2[(size_t)n * NCLS + c];
    for (int i = 0; i < dg; i += 8) {
        unsigned srcs[8];
        float w0[8], w1[8];
#pragma unroll
        for (int j = 0; j < 8; ++j) {
            const bool ok = (i + j) < dg;
            const int idx = ok ? (start + i + j) : start;
            const uint2 t = epk[idx];
            const float v = __builtin_bit_cast(float, t.y);
            srcs[j] = t.x;
            w0[j] = ok ? (1.f - v) : 0.f;
            w1[j] = ok ? v : 0.f;
        }
        unsigned g[8];
#pragma unroll
        for (int j = 0; j < 8; ++j) g[j] = hw01_u[(size_t)srcs[j] * NCLS + c];
#pragma unroll
        for (int j = 0; j < 8; ++j) {
            acc += w0[j] * bf2f((unsigned short)(g[j] & 0xFFFF));
            acc += w1[j] * bf2f((unsigned short)(g[j] >> 16));
        }
    }

    const float z = acc + b2[c];
    float m = z;
#pragma unroll
    for (int s = 1; s < 16; s <<= 1) m = fmaxf(m, __shfl_xor(m, s, 64));
    const float e = expf(z - m);
    float ssum = e;
#pragma unroll
    for (int s = 1; s < 16; s <<= 1) ssum += __shfl_xor(ssum, s, 64);
    out[(size_t)n * NCLS + c] = (z - m) - logf(ssum);
}

extern "C" void kernel_launch(void* const* d_in, const int* in_sizes, int n_in,
                              void* d_out, int out_size, void* d_ws, size_t ws_size,
                              hipStream_t stream) {
    const float* x = (const float*)d_in[0];
    const int* ei = (const int*)d_in[1];
    const float* ea = (const float*)d_in[2];
    const float* w1 = (const float*)d_in[3];
    const float* root1 = (const float*)d_in[4];
    const float* b1 = (const float*)d_in[5];
    const float* w2 = (const float*)d_in[6];
    const float* root2 = (const float*)d_in[7];
    const float* b2 = (const float*)d_in[8];
    float* out = (float*)d_out;

    char* ws = (char*)d_ws;
    unsigned short* xw01 = (unsigned short*)ws;                 // 25.6 MB
    float* aggH = (float*)(ws + 25600000);                      // 25.6 MB
    unsigned* hw01_u = (unsigned*)(ws + 51200000);              // 6.4 MB
    float* agg2 = (float*)(ws + 57600000);                      // 6.4 MB
    unsigned short* Bt = (unsigned short*)(ws + 64000000);      // 0.2 MB
    int* off = (int*)(ws + 64300000);                           // 0.4 MB (NPAD)
    int* deg = (int*)(ws + 64800000);                           // 0.4 MB (NPAD)
    int* bkcur = (int*)(ws + 65300000);                         // 1.6 KB
    uint2* epk = (uint2*)(ws + 65400000);                       // 25.6 MB (padded)
    uint2* epkS = (uint2*)(ws + 91100000);                      // 25.6 MB (padded)
                                                                // total ~116.7 MB << ~800 MB ws

    // CSR build (fixed-capacity bucket regions; no global histogram/scan)
    csr_bzero<<<1, 512, 0, stream>>>(bkcur);
    csr_bucket<<<(N_EDGES + EPB - 1) / EPB, 512, 0, stream>>>(ei, ea, bkcur, epk);
    csr_place<<<NBUK, 256, 0, stream>>>(bkcur, epk, epkS, off, deg);

    // layer 1
    k0_bt<<<192, 256, 0, stream>>>(w1, root1, Bt);
    k1_mfma<<<(N_NODES + 63) / 64, 256, 0, stream>>>(x, Bt, xw01, aggH);
    agg1<<<(N_NODES + 3) / 4, 256, 0, stream>>>(off, deg, epkS, (const unsigned*)xw01, aggH);

    // layer 2
    k3_relu_gemm<<<N_NODES / 16, 256, 0, stream>>>(aggH, b1, w2, root2, hw01_u, agg2);
    agg2_sm<<<N_NODES / 16, 256, 0, stream>>>(off, deg, epkS, hw01_u, agg2, b2, out);
}